// Round 13
// baseline (136.645 us; speedup 1.0000x reference)
//
#include <hip/hip_runtime.h>
#include <hip/hip_bf16.h>
#include <math.h>

#define N 4096
#define D 128
#define NJ 4
#define KTOP 16
#define CSPLIT 2

typedef __attribute__((ext_vector_type(8))) short bf16x8;
typedef __attribute__((ext_vector_type(4))) float f32x4;

// ws layout:
//   [0, 1MB)   fh   bf16 [N][D]       normalized feature rows, row-major
//   [1MB, 5MB) gh   bf16 [NJ][N*D]    normalized negative rows, FRAGMENT-MAJOR:
//              per j, per 64-cand chunk chg: 16 frags x 512 ushorts; frag (s,t)
//              lane l's 16B at chg*8192 + (s*4+t)*512 + l*8. Main's A-loads are
//              base + lane*16: perfectly coalesced (validated R10).
//   [5MB, 7MB) top  f32  [NJ][N][CSPLIT][16] partial sorted top-16 per col-split

__device__ __forceinline__ void bitonic_sort16_desc(float* a) {
    #pragma unroll
    for (int k = 2; k <= 16; k <<= 1) {
        #pragma unroll
        for (int jj = k >> 1; jj > 0; jj >>= 1) {
            #pragma unroll
            for (int i = 0; i < 16; i++) {
                int l = i ^ jj;
                if (l > i) {
                    bool up = ((i & k) == 0);
                    float x = a[i], y = a[l];
                    float mx = fmaxf(x, y), mn = fminf(x, y);
                    a[i] = up ? mx : mn;
                    a[l] = up ? mn : mx;
                }
            }
        }
    }
}

__device__ __forceinline__ void bitonic_clean16_desc(float* a) {
    #pragma unroll
    for (int jj = 8; jj > 0; jj >>= 1) {
        #pragma unroll
        for (int i = 0; i < 16; i++) {
            int l = i ^ jj;
            if (l > i) {
                float x = a[i], y = a[l];
                a[i] = fmaxf(x, y);
                a[l] = fminf(x, y);
            }
        }
    }
}

// ---------------- prep: LDS-staged normalize + repack, all-coalesced global I/O ----
// Block = 64 consecutive rows (one output chunk, 16 KB = 1024 uint4).
// Blocks 0..63 -> fh (row-major); blocks 64..319 -> gh (fragment-major).
// R12 BUG FIX: gh chunk stride is 1024 uint4 (was 512 -> chunks overlapped).
__global__ __launch_bounds__(256) void neguni_prep(
    const float* __restrict__ feat, const float* __restrict__ negs,
    unsigned short* __restrict__ fh, unsigned short* __restrict__ gh)
{
    __shared__ __align__(16) float fraw[64 * 132];       // 64 rows x 33 float4 (padded)
    __shared__ __align__(16) unsigned short obuf[8192];  // 16 KB bf16 out

    const int t = threadIdx.x;
    const int b = blockIdx.x;
    const bool is_f = (b < 64);

    // ---- pass 1: coalesced load of the block's 64 rows (32 KB fp32) ----
    const float4* src = is_f ? ((const float4*)feat) + (size_t)b * 2048
                             : ((const float4*)negs) + (size_t)(b - 64) * 2048;
    float4* frawv = (float4*)fraw;
    #pragma unroll
    for (int i = 0; i < 8; i++) {
        const int g = i * 256 + t;                 // float4 index 0..2047
        frawv[(g >> 5) * 33 + (g & 31)] = src[g];
    }
    __syncthreads();

    // ---- pass 2: norm + convert + repack into obuf ----
    const int row_l = t >> 2;        // 0..63
    const int s     = t & 3;         // 32-elem piece
    float4 v[8];
    #pragma unroll
    for (int k = 0; k < 8; k++) v[k] = frawv[row_l * 33 + s * 8 + k];

    float ss = 0.f;
    #pragma unroll
    for (int k = 0; k < 8; k++)
        ss += v[k].x * v[k].x + v[k].y * v[k].y + v[k].z * v[k].z + v[k].w * v[k].w;
    ss += __shfl_xor(ss, 1, 64);
    ss += __shfl_xor(ss, 2, 64);
    const float inv = 1.0f / fmaxf(sqrtf(ss), 1e-12f);

    const int tt  = row_l >> 4;
    const int col = row_l & 15;
    uint4* obufv = (uint4*)obuf;
    #pragma unroll
    for (int q = 0; q < 4; q++) {
        float fe[8] = {v[q*2].x, v[q*2].y, v[q*2].z, v[q*2].w,
                       v[q*2+1].x, v[q*2+1].y, v[q*2+1].z, v[q*2+1].w};
        unsigned int u[4];
        #pragma unroll
        for (int i = 0; i < 4; i++) {
            __hip_bfloat16 b0 = __float2bfloat16(fe[2*i]   * inv);
            __hip_bfloat16 b1 = __float2bfloat16(fe[2*i+1] * inv);
            u[i] = ((unsigned int)*(unsigned short*)&b1 << 16) | *(unsigned short*)&b0;
        }
        uint4 pk; pk.x = u[0]; pk.y = u[1]; pk.z = u[2]; pk.w = u[3];
        const int pos = is_f ? (row_l * 16 + s * 4 + q)                 // row-major
                             : ((s * 4 + tt) * 64 + q * 16 + col);      // fragment-major
        obufv[pos] = pk;
    }
    __syncthreads();

    // ---- pass 3: coalesced 16 KB store ----
    uint4* dst;
    if (is_f) {
        dst = ((uint4*)fh) + (size_t)b * 1024;
    } else {
        const int bn  = b - 64;
        const int j   = bn >> 6;
        const int chg = bn & 63;
        dst = ((uint4*)(gh + (size_t)j * N * D)) + (size_t)chg * 1024;
    }
    #pragma unroll
    for (int i = 0; i < 4; i++) dst[i * 256 + t] = obufv[i * 256 + t];
}

// ---------------- main: transposed MFMA + lane-local batched top-16 ----------------
// (byte-identical to R10's validated 71 µs kernel)
__global__ __launch_bounds__(256) void neguni_main(
    const unsigned short* __restrict__ fh, const unsigned short* __restrict__ gh,
    const int* __restrict__ target, const int* __restrict__ idxp,
    float* __restrict__ topbuf)
{
    __shared__ float tops[4][16][17];

    const int tid   = threadIdx.x;
    const int w     = tid >> 6;
    const int lane  = tid & 63;
    const int col16 = lane & 15;
    const int quad  = lane >> 4;

    const int j   = blockIdx.x & 3;
    const int ft  = (blockIdx.x >> 2) & 255;
    const int cs  = blockIdx.x >> 10;
    const int r0  = ft * 16;
    const int c0  = cs * 2048 + w * 512;
    const int idx = idxp[0];
    const bool msk = (j == idx);

    bf16x8 bfr[4];
    {
        const unsigned short* fr = fh + (size_t)(r0 + col16) * D + quad * 8;
        bfr[0] = *(const bf16x8*)(fr);
        bfr[1] = *(const bf16x8*)(fr + 32);
        bfr[2] = *(const bf16x8*)(fr + 64);
        bfr[3] = *(const bf16x8*)(fr + 96);
    }
    const int rtg = target[r0 + col16];

    float lst[KTOP];

    const int chg0 = cs * 32 + w * 8;
    const unsigned short* ab0 = gh + (size_t)j * N * D + (size_t)chg0 * 8192 + lane * 8;

    #pragma unroll 1
    for (int ch = 0; ch < 8; ch++) {
        const unsigned short* ab = ab0 + (size_t)ch * 8192;

        f32x4 acc[4];
        #pragma unroll
        for (int t = 0; t < 4; t++) acc[t] = (f32x4){0.f, 0.f, 0.f, 0.f};

        #pragma unroll
        for (int s = 0; s < 4; s++) {
            #pragma unroll
            for (int t = 0; t < 4; t++) {
                bf16x8 a = *(const bf16x8*)(ab + (s * 4 + t) * 512);
                acc[t] = __builtin_amdgcn_mfma_f32_16x16x32_bf16(a, bfr[s], acc[t], 0, 0, 0);
            }
        }

        const int cbase = c0 + ch * 64;
        float s16[16];
        #pragma unroll
        for (int t = 0; t < 4; t++) {
            s16[t * 4 + 0] = acc[t][0];
            s16[t * 4 + 1] = acc[t][1];
            s16[t * 4 + 2] = acc[t][2];
            s16[t * 4 + 3] = acc[t][3];
        }
        if (msk) {
            #pragma unroll
            for (int t = 0; t < 4; t++) {
                int4 tc = *(const int4*)(target + cbase + t * 16 + quad * 4);
                if (tc.x == rtg) s16[t * 4 + 0] = -1e9f;
                if (tc.y == rtg) s16[t * 4 + 1] = -1e9f;
                if (tc.z == rtg) s16[t * 4 + 2] = -1e9f;
                if (tc.w == rtg) s16[t * 4 + 3] = -1e9f;
            }
        }

        bitonic_sort16_desc(s16);
        if (ch == 0) {
            #pragma unroll
            for (int i = 0; i < 16; i++) lst[i] = s16[i];
        } else {
            float mg[16];
            #pragma unroll
            for (int i = 0; i < 16; i++) mg[i] = fmaxf(lst[i], s16[15 - i]);
            bitonic_clean16_desc(mg);
            #pragma unroll
            for (int i = 0; i < 16; i++) lst[i] = mg[i];
        }
    }

    #pragma unroll
    for (int off = 16; off <= 32; off <<= 1) {
        float mg[16];
        #pragma unroll
        for (int i = 0; i < 16; i++)
            mg[i] = fmaxf(lst[i], __shfl_xor(lst[15 - i], off, 64));
        bitonic_clean16_desc(mg);
        #pragma unroll
        for (int i = 0; i < 16; i++) lst[i] = mg[i];
    }

    if (lane < 16) {
        #pragma unroll
        for (int i = 0; i < 16; i++) tops[w][lane][i] = lst[i];
        tops[w][lane][16] = -3.0e38f;
    }
    __syncthreads();

    if (tid < 16) {
        int i0 = 0, i1 = 0, i2 = 0, i3 = 0;
        float* outp = topbuf + (((size_t)j * N + r0 + tid) * CSPLIT + cs) * KTOP;
        #pragma unroll
        for (int k = 0; k < KTOP; k++) {
            float v0 = tops[0][tid][i0], v1 = tops[1][tid][i1];
            float v2 = tops[2][tid][i2], v3 = tops[3][tid][i3];
            float m01 = fmaxf(v0, v1), m23 = fmaxf(v2, v3);
            float mx  = fmaxf(m01, m23);
            if      (mx == v0) i0++;
            else if (mx == v1) i1++;
            else if (mx == v2) i2++;
            else               i3++;
            outp[k] = mx;
        }
    }
}

// ---------------- finalize: 2-way merge of partials + entropy reduce ----------------
__global__ __launch_bounds__(256) void neguni_fin(
    const float* __restrict__ topbuf, float* __restrict__ out)
{
    __shared__ float buf[256][35];
    __shared__ float mm[64][65];
    __shared__ float red[4];

    const int t     = threadIdx.x;
    const int j     = t >> 6;
    const int row_l = t & 63;
    const int row   = blockIdx.x * 64 + row_l;

    const float4* src = (const float4*)(topbuf + ((size_t)j * N + row) * (CSPLIT * KTOP));
    #pragma unroll
    for (int q = 0; q < 8; q++) {
        float4 v = src[q];
        const int base = (q >> 2) * 17 + (q & 3) * 4;
        buf[t][base + 0] = v.x;
        buf[t][base + 1] = v.y;
        buf[t][base + 2] = v.z;
        buf[t][base + 3] = v.w;
    }
    buf[t][16] = -3.0e38f;
    buf[t][33] = -3.0e38f;

    {
        int ia = 0, ib = 17;
        #pragma unroll
        for (int k = 0; k < KTOP; k++) {
            float va = buf[t][ia], vb = buf[t][ib];
            bool ta = va >= vb;
            mm[row_l][k * 4 + j] = ta ? va : vb;
            if (ta) ia++; else ib++;
        }
    }
    __syncthreads();

    float val = 0.f;
    const float Ssum = (1.0f - powf(0.95f, 16.0f)) / 0.05f;
    #pragma unroll
    for (int i = 0; i < 4; i++) {
        const int idx = t + i * 256;
        const int rl  = idx & 63;
        const int k   = idx >> 6;
        float l0 = mm[rl][k * 4 + 0] * 100.0f;
        float l1 = mm[rl][k * 4 + 1] * 100.0f;
        float l2 = mm[rl][k * 4 + 2] * 100.0f;
        float l3 = mm[rl][k * 4 + 3] * 100.0f;
        float m  = fmaxf(fmaxf(l0, l1), fmaxf(l2, l3));
        float d0 = l0 - m, d1 = l1 - m, d2 = l2 - m, d3 = l3 - m;
        float e0 = expf(d0), e1 = expf(d1), e2 = expf(d2), e3 = expf(d3);
        float s  = e0 + e1 + e2 + e3;
        float ent = (e0 * d0 + e1 * d1 + e2 * d2 + e3 * d3) / s - logf(s);
        val += ent * powf(0.95f, (float)k);
    }
    val *= 1.0f / (Ssum * (float)N);

    #pragma unroll
    for (int off = 32; off > 0; off >>= 1) val += __shfl_xor(val, off, 64);
    if ((t & 63) == 0) red[t >> 6] = val;
    __syncthreads();
    if (t == 0) atomicAdd(out, red[0] + red[1] + red[2] + red[3]);
    if (blockIdx.x == 0 && t == 0) atomicAdd(out, logf(4.0f));
}

extern "C" void kernel_launch(void* const* d_in, const int* in_sizes, int n_in,
                              void* d_out, int out_size, void* d_ws, size_t ws_size,
                              hipStream_t stream) {
    const float* feat   = (const float*)d_in[0];
    const int*   target = (const int*)d_in[1];
    const float* negs   = (const float*)d_in[2];
    const int*   idxp   = (const int*)d_in[3];
    float* out = (float*)d_out;

    unsigned short* fh = (unsigned short*)d_ws;
    unsigned short* gh = fh + (size_t)N * D;                  // +1 MB
    float* topbuf      = (float*)(gh + (size_t)NJ * N * D);   // +5 MB, 2 MB long

    hipMemsetAsync(out, 0, sizeof(float), stream);
    neguni_prep<<<dim3((N + NJ * N) / 64), dim3(256), 0, stream>>>(feat, negs, fh, gh);
    neguni_main<<<dim3(NJ * (N / 16) * CSPLIT), dim3(256), 0, stream>>>(fh, gh, target, idxp, topbuf);
    neguni_fin<<<dim3(N / 64), dim3(256), 0, stream>>>(topbuf, out);
}